// Round 1
// baseline (361.482 us; speedup 1.0000x reference)
//
#include <hip/hip_runtime.h>
#include <hip/hip_bf16.h>
#include <math.h>

// Problem constants (fixed by the reference)
#define TT 4096   // tokens = B*S
#define PP 8192   // pairs  = TT*K
#define DD 1024   // model dim
#define HH 2048   // expert hidden
#define EE 8      // experts
#define CC1 4096  // 2H (up-proj width)

typedef __attribute__((ext_vector_type(8))) short s16x8;
typedef __attribute__((ext_vector_type(4))) float f32x4;

// ---------------- workspace layout (bytes) ----------------
#define W1T_OFF   0ull                                   // bf16 [E][4096][1024]  64 MB
#define W2T_OFF   (W1T_OFF + (size_t)EE*DD*CC1*2)        // bf16 [E][1024][2048]  32 MB
#define XB_OFF    (W2T_OFF + (size_t)EE*HH*DD*2)         // bf16 [T][1024]         8 MB
#define ABUF_OFF  (XB_OFF  + (size_t)TT*DD*2)            // bf16 [P][2048]        32 MB
#define DOWN_OFF  (ABUF_OFF + (size_t)PP*HH*2)           // f32  [P][1024]        32 MB
#define META_OFF  (DOWN_OFF + (size_t)PP*DD*4)           // int meta[256]
#define PAIR_OFF  (META_OFF + 1024)                      // int [P]
#define POS_OFF   (PAIR_OFF + (size_t)PP*4)              // int [P]

__device__ __forceinline__ unsigned short f2bf(float f) {
  union { float f; unsigned u; } a; a.f = f;
  unsigned u = a.u;
  unsigned r = u + 0x7FFFu + ((u >> 16) & 1u);   // round-to-nearest-even
  return (unsigned short)(r >> 16);
}

// ---------------- x -> bf16 ----------------
__global__ void k_cvt_x(const float* __restrict__ in, unsigned short* __restrict__ out, int n4) {
  int i = blockIdx.x * blockDim.x + threadIdx.x;
  if (i >= n4) return;
  float4 v = reinterpret_cast<const float4*>(in)[i];
  ushort4 o;
  o.x = f2bf(v.x); o.y = f2bf(v.y); o.z = f2bf(v.z); o.w = f2bf(v.w);
  reinterpret_cast<ushort4*>(out)[i] = o;
}

// ---------------- W [R][C] f32 -> Wt [C][R] bf16 (per matrix in grid.z) ----------------
__global__ void k_transpose(const float* __restrict__ in, unsigned short* __restrict__ out,
                            int R, int C) {
  __shared__ float t[32][33];
  const size_t mbase = (size_t)blockIdx.z * (size_t)R * (size_t)C;
  int c0 = blockIdx.x * 32, r0 = blockIdx.y * 32;
  int tx = threadIdx.x, ty = threadIdx.y;
#pragma unroll
  for (int i = 0; i < 4; ++i)
    t[ty + i*8][tx] = in[mbase + (size_t)(r0 + ty + i*8) * C + c0 + tx];
  __syncthreads();
#pragma unroll
  for (int i = 0; i < 4; ++i)
    out[mbase + (size_t)(c0 + ty + i*8) * R + r0 + tx] = f2bf(t[tx][ty + i*8]);
}

// ---------------- routing: bucket pairs by expert, tile list, inverse perm ----------------
// meta[0] = ntiles; meta[1..9] = offsets[0..8]; meta[16+2i],meta[17+2i] = (expert, q0) per tile
__global__ void k_route(const int* __restrict__ eidx, int* __restrict__ meta,
                        int* __restrict__ plist, int* __restrict__ pos) {
  __shared__ int cnt[EE], off[EE + 1], cur[EE];
  int tid = threadIdx.x;
  if (tid < EE) { cnt[tid] = 0; cur[tid] = 0; }
  __syncthreads();
  for (int p = tid; p < PP; p += blockDim.x) atomicAdd(&cnt[eidx[p]], 1);
  __syncthreads();
  if (tid == 0) {
    int s = 0;
    for (int e = 0; e < EE; ++e) { off[e] = s; s += cnt[e]; }
    off[EE] = s;
    int ntl = 0;
    for (int e = 0; e < EE; ++e)
      for (int r = 0; r < cnt[e]; r += 128) {
        meta[16 + 2*ntl]     = e;
        meta[16 + 2*ntl + 1] = off[e] + r;
        ++ntl;
      }
    meta[0] = ntl;
    for (int e = 0; e <= EE; ++e) meta[1 + e] = off[e];
  }
  __syncthreads();
  for (int p = tid; p < PP; p += blockDim.x) {
    int e = eidx[p];
    int q = off[e] + atomicAdd(&cur[e], 1);
    plist[q] = p;
    pos[p] = q;
  }
}

// ---------------- GEMM1: up = x @ W1[e], fused GLU + gate, bf16 out (sorted order) ----------
// grid: (72 tiles, 32 col-tiles of 64 h-cols); block 256 (4 waves x 32 rows)
__global__ __launch_bounds__(256) void k_gemm1(
    const unsigned short* __restrict__ xb,     // [T][1024] bf16
    const unsigned short* __restrict__ w1t,    // [E][4096][1024] bf16 (col-major: [col][k])
    const float* __restrict__ gates,           // [P] f32 (= expert_p flat)
    const int* __restrict__ meta,
    const int* __restrict__ plist,
    unsigned short* __restrict__ abuf)         // [P][2048] bf16
{
  const int nt = meta[0];
  const int tb = blockIdx.x;
  if (tb >= nt) return;
  const int e  = meta[16 + 2*tb];
  const int q0 = meta[16 + 2*tb + 1];
  const int nrows = min(128, meta[2 + e] - q0);  // offsets[e+1] - q0
  const int c0 = blockIdx.y * 64;

  __shared__ unsigned short blds[128][72];       // [col][k], +16B pad vs 128B stride

  const int tid = threadIdx.x;
  const int wave = tid >> 6, lane = tid & 63;
  const int l15 = lane & 15, l4 = lane >> 4;

  // Per-lane A row base pointers (A frag: row = lane&15, kblock = lane>>4)
  const unsigned short* arow[2];
#pragma unroll
  for (int rf = 0; rf < 2; ++rf) {
    int r = wave * 32 + rf * 16 + l15;
    int q = q0 + (r < nrows ? r : 0);
    int p = plist[q];
    arow[rf] = xb + (size_t)(p >> 1) * DD;
  }
  const unsigned short* w1e = w1t + (size_t)e * CC1 * DD;

  f32x4 acc[2][8];
#pragma unroll
  for (int a = 0; a < 2; ++a)
#pragma unroll
    for (int b = 0; b < 8; ++b) acc[a][b] = (f32x4)0.0f;

  for (int kk = 0; kk < DD; kk += 64) {
    __syncthreads();
#pragma unroll
    for (int i = 0; i < 4; ++i) {
      int chunk = i * 256 + tid;           // 1024 chunks of 8 bf16
      int ci = chunk >> 3;                 // 0..127 (0-63: h cols, 64-127: g cols)
      int ko = (chunk & 7) * 8;
      int col = (ci < 64) ? (c0 + ci) : (HH + c0 + (ci - 64));
      *reinterpret_cast<s16x8*>(&blds[ci][ko]) =
          *reinterpret_cast<const s16x8*>(w1e + (size_t)col * DD + kk + ko);
    }
    __syncthreads();
#pragma unroll
    for (int ks = 0; ks < 2; ++ks) {
      s16x8 af[2];
#pragma unroll
      for (int rf = 0; rf < 2; ++rf)
        af[rf] = *reinterpret_cast<const s16x8*>(arow[rf] + kk + ks * 32 + l4 * 8);
#pragma unroll
      for (int cf = 0; cf < 8; ++cf) {
        s16x8 bf = *reinterpret_cast<const s16x8*>(&blds[cf * 16 + l15][ks * 32 + l4 * 8]);
#pragma unroll
        for (int rf = 0; rf < 2; ++rf)
          acc[rf][cf] = __builtin_amdgcn_mfma_f32_16x16x32_bf16(af[rf], bf, acc[rf][cf], 0, 0, 0);
      }
    }
  }

  // Epilogue: a = gelu_exact(h) * (g+1) * gate, bf16, sorted row q
  // D frag: col = lane&15 (+cf*16), row = wave*32 + rf*16 + (lane>>4)*4 + i
#pragma unroll
  for (int rf = 0; rf < 2; ++rf) {
#pragma unroll
    for (int i = 0; i < 4; ++i) {
      int r = wave * 32 + rf * 16 + l4 * 4 + i;
      if (r < nrows) {
        int q = q0 + r;
        float gt = gates[plist[q]];
        unsigned short* orow = abuf + (size_t)q * HH + c0 + l15;
#pragma unroll
        for (int cf = 0; cf < 4; ++cf) {
          float hv = acc[rf][cf][i];
          float gv = acc[rf][cf + 4][i];
          float av = 0.5f * hv * (1.0f + erff(hv * 0.70710678118654752f)) * (gv + 1.0f) * gt;
          orow[cf * 16] = f2bf(av);
        }
      }
    }
  }
}

// ---------------- GEMM2: down = a @ W2[e], f32 out (sorted order, already gated) ----------
// grid: (72 tiles, 16 col-tiles of 64); block 256
__global__ __launch_bounds__(256) void k_gemm2(
    const unsigned short* __restrict__ abuf,   // [P][2048] bf16
    const unsigned short* __restrict__ w2t,    // [E][1024][2048] bf16 ([col][k])
    const int* __restrict__ meta,
    float* __restrict__ down)                  // [P][1024] f32
{
  const int nt = meta[0];
  const int tb = blockIdx.x;
  if (tb >= nt) return;
  const int e  = meta[16 + 2*tb];
  const int q0 = meta[16 + 2*tb + 1];
  const int nrows = min(128, meta[2 + e] - q0);
  const int c0 = blockIdx.y * 64;

  __shared__ unsigned short blds[64][72];

  const int tid = threadIdx.x;
  const int wave = tid >> 6, lane = tid & 63;
  const int l15 = lane & 15, l4 = lane >> 4;

  const unsigned short* arow[2];
#pragma unroll
  for (int rf = 0; rf < 2; ++rf) {
    int r = wave * 32 + rf * 16 + l15;
    int q = q0 + (r < nrows ? r : 0);
    arow[rf] = abuf + (size_t)q * HH;
  }
  const unsigned short* w2e = w2t + (size_t)e * DD * HH;

  f32x4 acc[2][4];
#pragma unroll
  for (int a = 0; a < 2; ++a)
#pragma unroll
    for (int b = 0; b < 4; ++b) acc[a][b] = (f32x4)0.0f;

  for (int kk = 0; kk < HH; kk += 64) {
    __syncthreads();
#pragma unroll
    for (int i = 0; i < 2; ++i) {
      int chunk = i * 256 + tid;           // 512 chunks
      int ci = chunk >> 3;                 // 0..63
      int ko = (chunk & 7) * 8;
      *reinterpret_cast<s16x8*>(&blds[ci][ko]) =
          *reinterpret_cast<const s16x8*>(w2e + (size_t)(c0 + ci) * HH + kk + ko);
    }
    __syncthreads();
#pragma unroll
    for (int ks = 0; ks < 2; ++ks) {
      s16x8 af[2];
#pragma unroll
      for (int rf = 0; rf < 2; ++rf)
        af[rf] = *reinterpret_cast<const s16x8*>(arow[rf] + kk + ks * 32 + l4 * 8);
#pragma unroll
      for (int cf = 0; cf < 4; ++cf) {
        s16x8 bf = *reinterpret_cast<const s16x8*>(&blds[cf * 16 + l15][ks * 32 + l4 * 8]);
#pragma unroll
        for (int rf = 0; rf < 2; ++rf)
          acc[rf][cf] = __builtin_amdgcn_mfma_f32_16x16x32_bf16(af[rf], bf, acc[rf][cf], 0, 0, 0);
      }
    }
  }

#pragma unroll
  for (int rf = 0; rf < 2; ++rf) {
#pragma unroll
    for (int i = 0; i < 4; ++i) {
      int r = wave * 32 + rf * 16 + l4 * 4 + i;
      if (r < nrows) {
        int q = q0 + r;
        float* orow = down + (size_t)q * DD + c0 + l15;
#pragma unroll
        for (int cf = 0; cf < 4; ++cf) orow[cf * 16] = acc[rf][cf][i];
      }
    }
  }
}

// ---------------- combine: y[t] = down[pos[2t]] + down[pos[2t+1]] ----------------
__global__ void k_combine(const float* __restrict__ down, const int* __restrict__ pos,
                          float* __restrict__ y) {
  int i = blockIdx.x * blockDim.x + threadIdx.x;  // over TT*DD/4
  if (i >= TT * DD / 4) return;
  int t = i >> 8;           // DD/4 = 256 float4 per row
  int c4 = i & 255;
  int qa = pos[2 * t], qb = pos[2 * t + 1];
  float4 a = reinterpret_cast<const float4*>(down + (size_t)qa * DD)[c4];
  float4 b = reinterpret_cast<const float4*>(down + (size_t)qb * DD)[c4];
  float4 o; o.x = a.x + b.x; o.y = a.y + b.y; o.z = a.z + b.z; o.w = a.w + b.w;
  reinterpret_cast<float4*>(y)[i] = o;
}

extern "C" void kernel_launch(void* const* d_in, const int* in_sizes, int n_in,
                              void* d_out, int out_size, void* d_ws, size_t ws_size,
                              hipStream_t stream) {
  const float* x  = (const float*)d_in[0];
  const float* ep = (const float*)d_in[1];
  const int*   ei = (const int*)d_in[2];
  const float* W1 = (const float*)d_in[3];
  const float* W2 = (const float*)d_in[4];
  float* y = (float*)d_out;
  char* ws = (char*)d_ws;

  unsigned short* w1t = (unsigned short*)(ws + W1T_OFF);
  unsigned short* w2t = (unsigned short*)(ws + W2T_OFF);
  unsigned short* xb  = (unsigned short*)(ws + XB_OFF);
  unsigned short* ab  = (unsigned short*)(ws + ABUF_OFF);
  float* down = (float*)(ws + DOWN_OFF);
  int* meta   = (int*)(ws + META_OFF);
  int* plist  = (int*)(ws + PAIR_OFF);
  int* pos    = (int*)(ws + POS_OFF);

  hipLaunchKernelGGL(k_cvt_x, dim3(TT * DD / 4 / 256), dim3(256), 0, stream,
                     x, xb, TT * DD / 4);
  hipLaunchKernelGGL(k_transpose, dim3(CC1 / 32, DD / 32, EE), dim3(32, 8), 0, stream,
                     W1, w1t, DD, CC1);
  hipLaunchKernelGGL(k_transpose, dim3(DD / 32, HH / 32, EE), dim3(32, 8), 0, stream,
                     W2, w2t, HH, DD);
  hipLaunchKernelGGL(k_route, dim3(1), dim3(256), 0, stream, ei, meta, plist, pos);
  hipLaunchKernelGGL(k_gemm1, dim3(72, 32), dim3(256), 0, stream,
                     xb, w1t, ep, meta, plist, ab);
  hipLaunchKernelGGL(k_gemm2, dim3(72, 16), dim3(256), 0, stream,
                     ab, w2t, meta, down);
  hipLaunchKernelGGL(k_combine, dim3(TT * DD / 4 / 256), dim3(256), 0, stream,
                     down, pos, y);
}

// Round 2
// 331.739 us; speedup vs baseline: 1.0897x; 1.0897x over previous
//
#include <hip/hip_runtime.h>
#include <hip/hip_bf16.h>
#include <math.h>

// Problem constants (fixed by the reference)
#define TT 4096   // tokens = B*S
#define PP 8192   // pairs  = TT*K
#define DD 1024   // model dim
#define HH 2048   // expert hidden
#define EE 8      // experts
#define CC1 4096  // 2H (up-proj width)

typedef __attribute__((ext_vector_type(8))) short s16x8;
typedef __attribute__((ext_vector_type(4))) float f32x4;

// ---------------- workspace layout (bytes) ----------------
#define W1T_OFF   0ull                                   // bf16 [E][4096][1024]  64 MB
#define W2T_OFF   (W1T_OFF + (size_t)EE*DD*CC1*2)        // bf16 [E][1024][2048]  32 MB
#define XB_OFF    (W2T_OFF + (size_t)EE*HH*DD*2)         // bf16 [T][1024]         8 MB
#define ABUF_OFF  (XB_OFF  + (size_t)TT*DD*2)            // bf16 [P][2048]        32 MB
#define DOWN_OFF  (ABUF_OFF + (size_t)PP*HH*2)           // f32  [P][1024]        32 MB
#define META_OFF  (DOWN_OFF + (size_t)PP*DD*4)           // int meta[256]
#define PAIR_OFF  (META_OFF + 1024)                      // int [P]
#define POS_OFF   (PAIR_OFF + (size_t)PP*4)              // int [P]

__device__ __forceinline__ unsigned short f2bf(float f) {
  union { float f; unsigned u; } a; a.f = f;
  unsigned u = a.u;
  unsigned r = u + 0x7FFFu + ((u >> 16) & 1u);   // round-to-nearest-even
  return (unsigned short)(r >> 16);
}

// async global->LDS, 16B per lane; LDS dest must be wave-uniform base + lane*16
__device__ __forceinline__ void gload16(const void* g, void* l) {
  __builtin_amdgcn_global_load_lds(
      (const __attribute__((address_space(1))) void*)(uintptr_t)g,
      (__attribute__((address_space(3))) void*)(unsigned)(uintptr_t)l,
      16, 0, 0);
}

// ---------------- x -> bf16 ----------------
__global__ void k_cvt_x(const float* __restrict__ in, unsigned short* __restrict__ out, int n4) {
  int i = blockIdx.x * blockDim.x + threadIdx.x;
  if (i >= n4) return;
  float4 v = reinterpret_cast<const float4*>(in)[i];
  ushort4 o;
  o.x = f2bf(v.x); o.y = f2bf(v.y); o.z = f2bf(v.z); o.w = f2bf(v.w);
  reinterpret_cast<ushort4*>(out)[i] = o;
}

// ---------------- W [R][C] f32 -> Wt [C][R] bf16 (per matrix in grid.z) ----------------
// 64x64 tile, 256 threads; float4 loads, ushort4 stores.
__global__ __launch_bounds__(256) void k_transpose(const float* __restrict__ in,
                                                   unsigned short* __restrict__ out,
                                                   int R, int C) {
  __shared__ float t[64][65];
  const size_t mbase = (size_t)blockIdx.z * (size_t)R * (size_t)C;
  int c0 = blockIdx.x * 64, r0 = blockIdx.y * 64;
  int tid = threadIdx.x;
#pragma unroll
  for (int i = 0; i < 4; ++i) {
    int ch = tid + i * 256;            // 1024 chunks of float4
    int row = ch >> 4, c4 = (ch & 15) * 4;
    float4 v = *reinterpret_cast<const float4*>(&in[mbase + (size_t)(r0 + row) * C + c0 + c4]);
    t[row][c4] = v.x; t[row][c4 + 1] = v.y; t[row][c4 + 2] = v.z; t[row][c4 + 3] = v.w;
  }
  __syncthreads();
#pragma unroll
  for (int i = 0; i < 4; ++i) {
    int ch = tid + i * 256;
    int c = ch >> 4, rb = (ch & 15) * 4;
    ushort4 o;
    o.x = f2bf(t[rb][c]); o.y = f2bf(t[rb + 1][c]);
    o.z = f2bf(t[rb + 2][c]); o.w = f2bf(t[rb + 3][c]);
    *reinterpret_cast<ushort4*>(&out[mbase + (size_t)(c0 + c) * R + r0 + rb]) = o;
  }
}

// ---------------- routing: bucket pairs by expert, tile list, inverse perm ----------------
// meta[0] = ntiles; meta[1..9] = offsets[0..8]; meta[16+2i],meta[17+2i] = (expert, q0) per tile
__global__ void k_route(const int* __restrict__ eidx, int* __restrict__ meta,
                        int* __restrict__ plist, int* __restrict__ pos) {
  __shared__ int cnt[EE], off[EE + 1], cur[EE];
  int tid = threadIdx.x;
  if (tid < EE) { cnt[tid] = 0; cur[tid] = 0; }
  __syncthreads();
  for (int p = tid; p < PP; p += blockDim.x) atomicAdd(&cnt[eidx[p]], 1);
  __syncthreads();
  if (tid == 0) {
    int s = 0;
    for (int e = 0; e < EE; ++e) { off[e] = s; s += cnt[e]; }
    off[EE] = s;
    int ntl = 0;
    for (int e = 0; e < EE; ++e)
      for (int r = 0; r < cnt[e]; r += 128) {
        meta[16 + 2*ntl]     = e;
        meta[16 + 2*ntl + 1] = off[e] + r;
        ++ntl;
      }
    meta[0] = ntl;
    for (int e = 0; e <= EE; ++e) meta[1 + e] = off[e];
  }
  __syncthreads();
  for (int p = tid; p < PP; p += blockDim.x) {
    int e = eidx[p];
    int q = off[e] + atomicAdd(&cur[e], 1);
    plist[q] = p;
    pos[p] = q;
  }
}

// ---------------- GEMM1: up = x @ W1[e], fused GLU + gate, bf16 out (sorted order) ----------
// m97 structure: 128x128 tile (64 h-cols paired with 64 g-cols), BK=64,
// A+B staged via global_load_lds width 16, 2 barriers / K-step.
// grid: (72 tiles, 32 col-tiles of 64 h-cols); block 256 (4 waves, 2x2)
__global__ __launch_bounds__(256) void k_gemm1(
    const unsigned short* __restrict__ xb,     // [T][1024] bf16
    const unsigned short* __restrict__ w1t,    // [E][4096][1024] bf16 ([col][k])
    const float* __restrict__ gates,           // [P] f32
    const int* __restrict__ meta,
    const int* __restrict__ plist,
    unsigned short* __restrict__ abuf)         // [P][2048] bf16
{
  const int nt = meta[0];
  const int tb = blockIdx.x;
  if (tb >= nt) return;
  const int e  = meta[16 + 2*tb];
  const int q0 = meta[16 + 2*tb + 1];
  const int nrows = min(128, meta[2 + e] - q0);
  const int c0 = blockIdx.y * 64;

  __shared__ unsigned short Asm[128 * 64];     // [row][k] linear
  __shared__ unsigned short Bsm[128 * 64];     // [colrow][k] linear

  const int tid = threadIdx.x;
  const int wave = tid >> 6, lane = tid & 63;
  const int l15 = lane & 15, l4 = lane >> 4;
  const int wr = wave >> 1, wc = wave & 1;

  const unsigned short* w1e = w1t + (size_t)e * CC1 * DD;

  // Per-thread staging sources (4 A chunks + 4 B chunks of 16B), rows fixed across K.
  const unsigned short* aga[4];
  const unsigned short* bga[4];
#pragma unroll
  for (int i = 0; i < 4; ++i) {
    int c = tid + i * 256;
    int row = c >> 3;
    int ko = (c & 7) * 8;                      // bf16 elements
    int r = row < nrows ? row : 0;
    int p = plist[q0 + r];
    aga[i] = xb + (size_t)(p >> 1) * DD + ko;
    // B LDS row -> global col: row = wcr*64 + s; s<32 -> h col, s>=32 -> g col
    int s = row & 63, wcr = row >> 6;
    int col = (s < 32) ? (c0 + wcr * 32 + s) : (HH + c0 + wcr * 32 + (s - 32));
    bga[i] = w1e + (size_t)col * DD + ko;
  }

  f32x4 acc[4][4];
#pragma unroll
  for (int a = 0; a < 4; ++a)
#pragma unroll
    for (int b = 0; b < 4; ++b) acc[a][b] = (f32x4)0.0f;

  for (int kk = 0; kk < DD; kk += 64) {
#pragma unroll
    for (int i = 0; i < 4; ++i) {
      int c = tid + i * 256;
      gload16(aga[i] + kk, &Asm[c * 8]);
      gload16(bga[i] + kk, &Bsm[c * 8]);
    }
    __syncthreads();                            // drains vmcnt -> LDS ready
#pragma unroll
    for (int ks = 0; ks < 2; ++ks) {
      s16x8 af[4], bfr[4];
#pragma unroll
      for (int rf = 0; rf < 4; ++rf)
        af[rf] = *reinterpret_cast<const s16x8*>(&Asm[(wr * 64 + rf * 16 + l15) * 64 + ks * 32 + l4 * 8]);
#pragma unroll
      for (int cf = 0; cf < 4; ++cf)
        bfr[cf] = *reinterpret_cast<const s16x8*>(&Bsm[(wc * 64 + cf * 16 + l15) * 64 + ks * 32 + l4 * 8]);
#pragma unroll
      for (int rf = 0; rf < 4; ++rf)
#pragma unroll
        for (int cf = 0; cf < 4; ++cf)
          acc[rf][cf] = __builtin_amdgcn_mfma_f32_16x16x32_bf16(af[rf], bfr[cf], acc[rf][cf], 0, 0, 0);
    }
    __syncthreads();                            // all waves done reading before next stage
  }

  // Epilogue: a = gelu_exact(h) * (g+1) * gate, bf16.
  // acc[rf][cf] with cf in {0,1} = h cols, {2,3} = matching g cols (same wave).
#pragma unroll
  for (int rf = 0; rf < 4; ++rf) {
#pragma unroll
    for (int i = 0; i < 4; ++i) {
      int r = wr * 64 + rf * 16 + l4 * 4 + i;
      if (r < nrows) {
        int q = q0 + r;
        float gt = gates[plist[q]];
        unsigned short* orow = abuf + (size_t)q * HH + c0 + wc * 32 + l15;
#pragma unroll
        for (int cf = 0; cf < 2; ++cf) {
          float hv = acc[rf][cf][i];
          float gv = acc[rf][cf + 2][i];
          float av = 0.5f * hv * (1.0f + erff(hv * 0.70710678118654752f)) * (gv + 1.0f) * gt;
          orow[cf * 16] = f2bf(av);
        }
      }
    }
  }
}

// ---------------- GEMM2: down = a @ W2[e], f32 out (sorted order, already gated) ----------
// grid: (72 tiles, 8 col-tiles of 128); block 256 (4 waves, 2x2)
__global__ __launch_bounds__(256) void k_gemm2(
    const unsigned short* __restrict__ abuf,   // [P][2048] bf16
    const unsigned short* __restrict__ w2t,    // [E][1024][2048] bf16 ([col][k])
    const int* __restrict__ meta,
    float* __restrict__ down)                  // [P][1024] f32
{
  const int nt = meta[0];
  const int tb = blockIdx.x;
  if (tb >= nt) return;
  const int e  = meta[16 + 2*tb];
  const int q0 = meta[16 + 2*tb + 1];
  const int nrows = min(128, meta[2 + e] - q0);
  const int c0 = blockIdx.y * 128;

  __shared__ unsigned short Asm[128 * 64];
  __shared__ unsigned short Bsm[128 * 64];

  const int tid = threadIdx.x;
  const int wave = tid >> 6, lane = tid & 63;
  const int l15 = lane & 15, l4 = lane >> 4;
  const int wr = wave >> 1, wc = wave & 1;

  const unsigned short* w2e = w2t + (size_t)e * DD * HH;

  const unsigned short* aga[4];
  const unsigned short* bga[4];
#pragma unroll
  for (int i = 0; i < 4; ++i) {
    int c = tid + i * 256;
    int row = c >> 3;
    int ko = (c & 7) * 8;
    int r = row < nrows ? row : 0;
    aga[i] = abuf + (size_t)(q0 + r) * HH + ko;
    bga[i] = w2e + (size_t)(c0 + row) * HH + ko;
  }

  f32x4 acc[4][4];
#pragma unroll
  for (int a = 0; a < 4; ++a)
#pragma unroll
    for (int b = 0; b < 4; ++b) acc[a][b] = (f32x4)0.0f;

  for (int kk = 0; kk < HH; kk += 64) {
#pragma unroll
    for (int i = 0; i < 4; ++i) {
      int c = tid + i * 256;
      gload16(aga[i] + kk, &Asm[c * 8]);
      gload16(bga[i] + kk, &Bsm[c * 8]);
    }
    __syncthreads();
#pragma unroll
    for (int ks = 0; ks < 2; ++ks) {
      s16x8 af[4], bfr[4];
#pragma unroll
      for (int rf = 0; rf < 4; ++rf)
        af[rf] = *reinterpret_cast<const s16x8*>(&Asm[(wr * 64 + rf * 16 + l15) * 64 + ks * 32 + l4 * 8]);
#pragma unroll
      for (int cf = 0; cf < 4; ++cf)
        bfr[cf] = *reinterpret_cast<const s16x8*>(&Bsm[(wc * 64 + cf * 16 + l15) * 64 + ks * 32 + l4 * 8]);
#pragma unroll
      for (int rf = 0; rf < 4; ++rf)
#pragma unroll
        for (int cf = 0; cf < 4; ++cf)
          acc[rf][cf] = __builtin_amdgcn_mfma_f32_16x16x32_bf16(af[rf], bfr[cf], acc[rf][cf], 0, 0, 0);
    }
    __syncthreads();
  }

#pragma unroll
  for (int rf = 0; rf < 4; ++rf) {
#pragma unroll
    for (int i = 0; i < 4; ++i) {
      int r = wr * 64 + rf * 16 + l4 * 4 + i;
      if (r < nrows) {
        int q = q0 + r;
        float* orow = down + (size_t)q * DD + c0 + wc * 64 + l15;
#pragma unroll
        for (int cf = 0; cf < 4; ++cf) orow[cf * 16] = acc[rf][cf][i];
      }
    }
  }
}

// ---------------- combine: y[t] = down[pos[2t]] + down[pos[2t+1]] ----------------
__global__ void k_combine(const float* __restrict__ down, const int* __restrict__ pos,
                          float* __restrict__ y) {
  int i = blockIdx.x * blockDim.x + threadIdx.x;  // over TT*DD/4
  if (i >= TT * DD / 4) return;
  int t = i >> 8;           // DD/4 = 256 float4 per row
  int c4 = i & 255;
  int qa = pos[2 * t], qb = pos[2 * t + 1];
  float4 a = reinterpret_cast<const float4*>(down + (size_t)qa * DD)[c4];
  float4 b = reinterpret_cast<const float4*>(down + (size_t)qb * DD)[c4];
  float4 o; o.x = a.x + b.x; o.y = a.y + b.y; o.z = a.z + b.z; o.w = a.w + b.w;
  reinterpret_cast<float4*>(y)[i] = o;
}

extern "C" void kernel_launch(void* const* d_in, const int* in_sizes, int n_in,
                              void* d_out, int out_size, void* d_ws, size_t ws_size,
                              hipStream_t stream) {
  const float* x  = (const float*)d_in[0];
  const float* ep = (const float*)d_in[1];
  const int*   ei = (const int*)d_in[2];
  const float* W1 = (const float*)d_in[3];
  const float* W2 = (const float*)d_in[4];
  float* y = (float*)d_out;
  char* ws = (char*)d_ws;

  unsigned short* w1t = (unsigned short*)(ws + W1T_OFF);
  unsigned short* w2t = (unsigned short*)(ws + W2T_OFF);
  unsigned short* xb  = (unsigned short*)(ws + XB_OFF);
  unsigned short* ab  = (unsigned short*)(ws + ABUF_OFF);
  float* down = (float*)(ws + DOWN_OFF);
  int* meta   = (int*)(ws + META_OFF);
  int* plist  = (int*)(ws + PAIR_OFF);
  int* pos    = (int*)(ws + POS_OFF);

  hipLaunchKernelGGL(k_cvt_x, dim3(TT * DD / 4 / 256), dim3(256), 0, stream,
                     x, xb, TT * DD / 4);
  hipLaunchKernelGGL(k_transpose, dim3(CC1 / 64, DD / 64, EE), dim3(256), 0, stream,
                     W1, w1t, DD, CC1);
  hipLaunchKernelGGL(k_transpose, dim3(DD / 64, HH / 64, EE), dim3(256), 0, stream,
                     W2, w2t, HH, DD);
  hipLaunchKernelGGL(k_route, dim3(1), dim3(256), 0, stream, ei, meta, plist, pos);
  hipLaunchKernelGGL(k_gemm1, dim3(72, 32), dim3(256), 0, stream,
                     xb, w1t, ep, meta, plist, ab);
  hipLaunchKernelGGL(k_gemm2, dim3(72, 8), dim3(256), 0, stream,
                     ab, w2t, meta, down);
  hipLaunchKernelGGL(k_combine, dim3(TT * DD / 4 / 256), dim3(256), 0, stream,
                     down, pos, y);
}

// Round 3
// 307.461 us; speedup vs baseline: 1.1757x; 1.0790x over previous
//
#include <hip/hip_runtime.h>
#include <hip/hip_bf16.h>
#include <math.h>

// Problem constants (fixed by the reference)
#define TT 4096   // tokens = B*S
#define PP 8192   // pairs  = TT*K
#define DD 1024   // model dim
#define HH 2048   // expert hidden
#define EE 8      // experts
#define CC1 4096  // 2H (up-proj width)

typedef __attribute__((ext_vector_type(8))) short s16x8;
typedef __attribute__((ext_vector_type(4))) float f32x4;

// ---------------- workspace layout (bytes) ----------------
#define W1T_OFF   0ull                                   // bf16 [E][4096][1024]  64 MB
#define W2T_OFF   (W1T_OFF + (size_t)EE*DD*CC1*2)        // bf16 [E][1024][2048]  32 MB
#define XB_OFF    (W2T_OFF + (size_t)EE*HH*DD*2)         // bf16 [T][1024]         8 MB
#define ABUF_OFF  (XB_OFF  + (size_t)TT*DD*2)            // bf16 [P][2048]        32 MB
#define DOWN_OFF  (ABUF_OFF + (size_t)PP*HH*2)           // f32  [P][1024]        32 MB
#define META_OFF  (DOWN_OFF + (size_t)PP*DD*4)           // int meta[256]
#define PAIR_OFF  (META_OFF + 1024)                      // int [P]
#define POS_OFF   (PAIR_OFF + (size_t)PP*4)              // int [P]

__device__ __forceinline__ unsigned short f2bf(float f) {
  union { float f; unsigned u; } a; a.f = f;
  unsigned u = a.u;
  unsigned r = u + 0x7FFFu + ((u >> 16) & 1u);   // round-to-nearest-even
  return (unsigned short)(r >> 16);
}

// async global->LDS, 16B per lane; LDS dest must be wave-uniform base + lane*16
__device__ __forceinline__ void gload16(const void* g, void* l) {
  __builtin_amdgcn_global_load_lds(
      (const __attribute__((address_space(1))) void*)(uintptr_t)g,
      (__attribute__((address_space(3))) void*)(unsigned)(uintptr_t)l,
      16, 0, 0);
}

// ---------------- x -> bf16 ----------------
__global__ void k_cvt_x(const float* __restrict__ in, unsigned short* __restrict__ out, int n4) {
  int i = blockIdx.x * blockDim.x + threadIdx.x;
  if (i >= n4) return;
  float4 v = reinterpret_cast<const float4*>(in)[i];
  ushort4 o;
  o.x = f2bf(v.x); o.y = f2bf(v.y); o.z = f2bf(v.z); o.w = f2bf(v.w);
  reinterpret_cast<ushort4*>(out)[i] = o;
}

// ---------------- W [R][C] f32 -> Wt [C][R] bf16 (per matrix in grid.z) ----------------
__global__ __launch_bounds__(256) void k_transpose(const float* __restrict__ in,
                                                   unsigned short* __restrict__ out,
                                                   int R, int C) {
  __shared__ float t[64][65];
  const size_t mbase = (size_t)blockIdx.z * (size_t)R * (size_t)C;
  int c0 = blockIdx.x * 64, r0 = blockIdx.y * 64;
  int tid = threadIdx.x;
#pragma unroll
  for (int i = 0; i < 4; ++i) {
    int ch = tid + i * 256;            // 1024 chunks of float4
    int row = ch >> 4, c4 = (ch & 15) * 4;
    float4 v = *reinterpret_cast<const float4*>(&in[mbase + (size_t)(r0 + row) * C + c0 + c4]);
    t[row][c4] = v.x; t[row][c4 + 1] = v.y; t[row][c4 + 2] = v.z; t[row][c4 + 3] = v.w;
  }
  __syncthreads();
#pragma unroll
  for (int i = 0; i < 4; ++i) {
    int ch = tid + i * 256;
    int c = ch >> 4, rb = (ch & 15) * 4;
    ushort4 o;
    o.x = f2bf(t[rb][c]); o.y = f2bf(t[rb + 1][c]);
    o.z = f2bf(t[rb + 2][c]); o.w = f2bf(t[rb + 3][c]);
    *reinterpret_cast<ushort4*>(&out[mbase + (size_t)(c0 + c) * R + r0 + rb]) = o;
  }
}

// ---------------- routing: bucket pairs by expert, tile list, inverse perm ----------------
// meta[0] = ntiles; meta[1..9] = offsets[0..8]; meta[16+2i],meta[17+2i] = (expert, q0) per tile
__global__ void k_route(const int* __restrict__ eidx, int* __restrict__ meta,
                        int* __restrict__ plist, int* __restrict__ pos) {
  __shared__ int cnt[EE], off[EE + 1], cur[EE];
  int tid = threadIdx.x;
  if (tid < EE) { cnt[tid] = 0; cur[tid] = 0; }
  __syncthreads();
  for (int p = tid; p < PP; p += blockDim.x) atomicAdd(&cnt[eidx[p]], 1);
  __syncthreads();
  if (tid == 0) {
    int s = 0;
    for (int e = 0; e < EE; ++e) { off[e] = s; s += cnt[e]; }
    off[EE] = s;
    int ntl = 0;
    for (int e = 0; e < EE; ++e)
      for (int r = 0; r < cnt[e]; r += 128) {
        meta[16 + 2*ntl]     = e;
        meta[16 + 2*ntl + 1] = off[e] + r;
        ++ntl;
      }
    meta[0] = ntl;
    for (int e = 0; e <= EE; ++e) meta[1 + e] = off[e];
  }
  __syncthreads();
  for (int p = tid; p < PP; p += blockDim.x) {
    int e = eidx[p];
    int q = off[e] + atomicAdd(&cur[e], 1);
    plist[q] = p;
    pos[p] = q;
  }
}

// ---------------- GEMM1: up = x @ W1[e], fused GLU + gate, bf16 out (sorted order) ----------
// 128x128 tile (64 h-cols paired with 64 g-cols), BK=64, double-buffered LDS:
// STAGE(next) issued before COMPUTE(cur), ONE vmcnt(0)+barrier (__syncthreads) per K-step.
// grid: (72 tiles, 32 col-tiles of 64 h-cols); block 256 (4 waves, 2x2)
__global__ __launch_bounds__(256) void k_gemm1(
    const unsigned short* __restrict__ xb,     // [T][1024] bf16
    const unsigned short* __restrict__ w1t,    // [E][4096][1024] bf16 ([col][k])
    const float* __restrict__ gates,           // [P] f32
    const int* __restrict__ meta,
    const int* __restrict__ plist,
    unsigned short* __restrict__ abuf)         // [P][2048] bf16
{
  const int nt = meta[0];
  const int tb = blockIdx.x;
  if (tb >= nt) return;
  const int e  = meta[16 + 2*tb];
  const int q0 = meta[16 + 2*tb + 1];
  const int nrows = min(128, meta[2 + e] - q0);
  const int c0 = blockIdx.y * 64;

  __shared__ unsigned short Asm[2][128 * 64];
  __shared__ unsigned short Bsm[2][128 * 64];

  const int tid = threadIdx.x;
  const int wave = tid >> 6, lane = tid & 63;
  const int l15 = lane & 15, l4 = lane >> 4;
  const int wr = wave >> 1, wc = wave & 1;

  const unsigned short* w1e = w1t + (size_t)e * CC1 * DD;

  const unsigned short* aga[4];
  const unsigned short* bga[4];
#pragma unroll
  for (int i = 0; i < 4; ++i) {
    int c = tid + i * 256;
    int row = c >> 3;
    int ko = (c & 7) * 8;                      // bf16 elements
    int r = row < nrows ? row : 0;
    int p = plist[q0 + r];
    aga[i] = xb + (size_t)(p >> 1) * DD + ko;
    int u = row & 63, wcq = row >> 6;
    int col = (u < 32) ? (c0 + wcq * 32 + u) : (HH + c0 + wcq * 32 + (u - 32));
    bga[i] = w1e + (size_t)col * DD + ko;
  }

  f32x4 acc[4][4];
#pragma unroll
  for (int a = 0; a < 4; ++a)
#pragma unroll
    for (int b = 0; b < 4; ++b) acc[a][b] = (f32x4)0.0f;

  // prologue: stage K-tile 0 into buffer 0
#pragma unroll
  for (int i = 0; i < 4; ++i) {
    int c = tid + i * 256;
    gload16(aga[i], &Asm[0][c * 8]);
    gload16(bga[i], &Bsm[0][c * 8]);
  }
  __syncthreads();

  int cur = 0;
  for (int kt = 0; kt < DD / 64 - 1; ++kt) {
    const int kk = (kt + 1) * 64;
    // issue next-tile loads FIRST (they fly under the MFMAs below)
#pragma unroll
    for (int i = 0; i < 4; ++i) {
      int c = tid + i * 256;
      gload16(aga[i] + kk, &Asm[cur ^ 1][c * 8]);
      gload16(bga[i] + kk, &Bsm[cur ^ 1][c * 8]);
    }
    // compute current tile
#pragma unroll
    for (int ks = 0; ks < 2; ++ks) {
      s16x8 af[4], bfr[4];
#pragma unroll
      for (int rf = 0; rf < 4; ++rf)
        af[rf] = *reinterpret_cast<const s16x8*>(&Asm[cur][(wr * 64 + rf * 16 + l15) * 64 + ks * 32 + l4 * 8]);
#pragma unroll
      for (int cf = 0; cf < 4; ++cf)
        bfr[cf] = *reinterpret_cast<const s16x8*>(&Bsm[cur][(wc * 64 + cf * 16 + l15) * 64 + ks * 32 + l4 * 8]);
#pragma unroll
      for (int rf = 0; rf < 4; ++rf)
#pragma unroll
        for (int cf = 0; cf < 4; ++cf)
          acc[rf][cf] = __builtin_amdgcn_mfma_f32_16x16x32_bf16(af[rf], bfr[cf], acc[rf][cf], 0, 0, 0);
    }
    __syncthreads();   // vmcnt(0)+lgkmcnt(0)+barrier: next tile staged & visible
    cur ^= 1;
  }
  // epilogue K-tile (no prefetch)
#pragma unroll
  for (int ks = 0; ks < 2; ++ks) {
    s16x8 af[4], bfr[4];
#pragma unroll
    for (int rf = 0; rf < 4; ++rf)
      af[rf] = *reinterpret_cast<const s16x8*>(&Asm[cur][(wr * 64 + rf * 16 + l15) * 64 + ks * 32 + l4 * 8]);
#pragma unroll
    for (int cf = 0; cf < 4; ++cf)
      bfr[cf] = *reinterpret_cast<const s16x8*>(&Bsm[cur][(wc * 64 + cf * 16 + l15) * 64 + ks * 32 + l4 * 8]);
#pragma unroll
    for (int rf = 0; rf < 4; ++rf)
#pragma unroll
      for (int cf = 0; cf < 4; ++cf)
        acc[rf][cf] = __builtin_amdgcn_mfma_f32_16x16x32_bf16(af[rf], bfr[cf], acc[rf][cf], 0, 0, 0);
  }

  // Epilogue: a = gelu_exact(h) * (g+1) * gate, bf16.
  // acc[rf][cf] with cf in {0,1} = h cols, {2,3} = matching g cols (same wave).
#pragma unroll
  for (int rf = 0; rf < 4; ++rf) {
#pragma unroll
    for (int i = 0; i < 4; ++i) {
      int r = wr * 64 + rf * 16 + l4 * 4 + i;
      if (r < nrows) {
        int q = q0 + r;
        float gt = gates[plist[q]];
        unsigned short* orow = abuf + (size_t)q * HH + c0 + wc * 32 + l15;
#pragma unroll
        for (int cf = 0; cf < 2; ++cf) {
          float hv = acc[rf][cf][i];
          float gv = acc[rf][cf + 2][i];
          float av = 0.5f * hv * (1.0f + erff(hv * 0.70710678118654752f)) * (gv + 1.0f) * gt;
          orow[cf * 16] = f2bf(av);
        }
      }
    }
  }
}

// ---------------- GEMM2: down = a @ W2[e], f32 out (sorted order, already gated) ----------
// Same double-buffered 2-phase structure; grid: (72 tiles, 8 col-tiles of 128); block 256
__global__ __launch_bounds__(256) void k_gemm2(
    const unsigned short* __restrict__ abuf,   // [P][2048] bf16
    const unsigned short* __restrict__ w2t,    // [E][1024][2048] bf16 ([col][k])
    const int* __restrict__ meta,
    float* __restrict__ down)                  // [P][1024] f32
{
  const int nt = meta[0];
  const int tb = blockIdx.x;
  if (tb >= nt) return;
  const int e  = meta[16 + 2*tb];
  const int q0 = meta[16 + 2*tb + 1];
  const int nrows = min(128, meta[2 + e] - q0);
  const int c0 = blockIdx.y * 128;

  __shared__ unsigned short Asm[2][128 * 64];
  __shared__ unsigned short Bsm[2][128 * 64];

  const int tid = threadIdx.x;
  const int wave = tid >> 6, lane = tid & 63;
  const int l15 = lane & 15, l4 = lane >> 4;
  const int wr = wave >> 1, wc = wave & 1;

  const unsigned short* w2e = w2t + (size_t)e * DD * HH;

  const unsigned short* aga[4];
  const unsigned short* bga[4];
#pragma unroll
  for (int i = 0; i < 4; ++i) {
    int c = tid + i * 256;
    int row = c >> 3;
    int ko = (c & 7) * 8;
    int r = row < nrows ? row : 0;
    aga[i] = abuf + (size_t)(q0 + r) * HH + ko;
    bga[i] = w2e + (size_t)(c0 + row) * HH + ko;
  }

  f32x4 acc[4][4];
#pragma unroll
  for (int a = 0; a < 4; ++a)
#pragma unroll
    for (int b = 0; b < 4; ++b) acc[a][b] = (f32x4)0.0f;

#pragma unroll
  for (int i = 0; i < 4; ++i) {
    int c = tid + i * 256;
    gload16(aga[i], &Asm[0][c * 8]);
    gload16(bga[i], &Bsm[0][c * 8]);
  }
  __syncthreads();

  int cur = 0;
  for (int kt = 0; kt < HH / 64 - 1; ++kt) {
    const int kk = (kt + 1) * 64;
#pragma unroll
    for (int i = 0; i < 4; ++i) {
      int c = tid + i * 256;
      gload16(aga[i] + kk, &Asm[cur ^ 1][c * 8]);
      gload16(bga[i] + kk, &Bsm[cur ^ 1][c * 8]);
    }
#pragma unroll
    for (int ks = 0; ks < 2; ++ks) {
      s16x8 af[4], bfr[4];
#pragma unroll
      for (int rf = 0; rf < 4; ++rf)
        af[rf] = *reinterpret_cast<const s16x8*>(&Asm[cur][(wr * 64 + rf * 16 + l15) * 64 + ks * 32 + l4 * 8]);
#pragma unroll
      for (int cf = 0; cf < 4; ++cf)
        bfr[cf] = *reinterpret_cast<const s16x8*>(&Bsm[cur][(wc * 64 + cf * 16 + l15) * 64 + ks * 32 + l4 * 8]);
#pragma unroll
      for (int rf = 0; rf < 4; ++rf)
#pragma unroll
        for (int cf = 0; cf < 4; ++cf)
          acc[rf][cf] = __builtin_amdgcn_mfma_f32_16x16x32_bf16(af[rf], bfr[cf], acc[rf][cf], 0, 0, 0);
    }
    __syncthreads();
    cur ^= 1;
  }
#pragma unroll
  for (int ks = 0; ks < 2; ++ks) {
    s16x8 af[4], bfr[4];
#pragma unroll
    for (int rf = 0; rf < 4; ++rf)
      af[rf] = *reinterpret_cast<const s16x8*>(&Asm[cur][(wr * 64 + rf * 16 + l15) * 64 + ks * 32 + l4 * 8]);
#pragma unroll
    for (int cf = 0; cf < 4; ++cf)
      bfr[cf] = *reinterpret_cast<const s16x8*>(&Bsm[cur][(wc * 64 + cf * 16 + l15) * 64 + ks * 32 + l4 * 8]);
#pragma unroll
    for (int rf = 0; rf < 4; ++rf)
#pragma unroll
      for (int cf = 0; cf < 4; ++cf)
        acc[rf][cf] = __builtin_amdgcn_mfma_f32_16x16x32_bf16(af[rf], bfr[cf], acc[rf][cf], 0, 0, 0);
  }

#pragma unroll
  for (int rf = 0; rf < 4; ++rf) {
#pragma unroll
    for (int i = 0; i < 4; ++i) {
      int r = wr * 64 + rf * 16 + l4 * 4 + i;
      if (r < nrows) {
        int q = q0 + r;
        float* orow = down + (size_t)q * DD + c0 + wc * 64 + l15;
#pragma unroll
        for (int cf = 0; cf < 4; ++cf) orow[cf * 16] = acc[rf][cf][i];
      }
    }
  }
}

// ---------------- combine: y[t] = down[pos[2t]] + down[pos[2t+1]] ----------------
__global__ void k_combine(const float* __restrict__ down, const int* __restrict__ pos,
                          float* __restrict__ y) {
  int i = blockIdx.x * blockDim.x + threadIdx.x;  // over TT*DD/4
  if (i >= TT * DD / 4) return;
  int t = i >> 8;           // DD/4 = 256 float4 per row
  int c4 = i & 255;
  int qa = pos[2 * t], qb = pos[2 * t + 1];
  float4 a = reinterpret_cast<const float4*>(down + (size_t)qa * DD)[c4];
  float4 b = reinterpret_cast<const float4*>(down + (size_t)qb * DD)[c4];
  float4 o; o.x = a.x + b.x; o.y = a.y + b.y; o.z = a.z + b.z; o.w = a.w + b.w;
  reinterpret_cast<float4*>(y)[i] = o;
}

extern "C" void kernel_launch(void* const* d_in, const int* in_sizes, int n_in,
                              void* d_out, int out_size, void* d_ws, size_t ws_size,
                              hipStream_t stream) {
  const float* x  = (const float*)d_in[0];
  const float* ep = (const float*)d_in[1];
  const int*   ei = (const int*)d_in[2];
  const float* W1 = (const float*)d_in[3];
  const float* W2 = (const float*)d_in[4];
  float* y = (float*)d_out;
  char* ws = (char*)d_ws;

  unsigned short* w1t = (unsigned short*)(ws + W1T_OFF);
  unsigned short* w2t = (unsigned short*)(ws + W2T_OFF);
  unsigned short* xb  = (unsigned short*)(ws + XB_OFF);
  unsigned short* ab  = (unsigned short*)(ws + ABUF_OFF);
  float* down = (float*)(ws + DOWN_OFF);
  int* meta   = (int*)(ws + META_OFF);
  int* plist  = (int*)(ws + PAIR_OFF);
  int* pos    = (int*)(ws + POS_OFF);

  hipLaunchKernelGGL(k_cvt_x, dim3(TT * DD / 4 / 256), dim3(256), 0, stream,
                     x, xb, TT * DD / 4);
  hipLaunchKernelGGL(k_transpose, dim3(CC1 / 64, DD / 64, EE), dim3(256), 0, stream,
                     W1, w1t, DD, CC1);
  hipLaunchKernelGGL(k_transpose, dim3(DD / 64, HH / 64, EE), dim3(256), 0, stream,
                     W2, w2t, HH, DD);
  hipLaunchKernelGGL(k_route, dim3(1), dim3(256), 0, stream, ei, meta, plist, pos);
  hipLaunchKernelGGL(k_gemm1, dim3(72, 32), dim3(256), 0, stream,
                     xb, w1t, ep, meta, plist, ab);
  hipLaunchKernelGGL(k_gemm2, dim3(72, 8), dim3(256), 0, stream,
                     ab, w2t, meta, down);
  hipLaunchKernelGGL(k_combine, dim3(TT * DD / 4 / 256), dim3(256), 0, stream,
                     down, pos, y);
}